// Round 3
// baseline (1591.522 us; speedup 1.0000x reference)
//
#include <hip/hip_runtime.h>
#include <hip/hip_bf16.h>
#include <cstddef>

#define B_ 4
#define S_ 2048
#define D_ 2048
#define H_ 16
#define DH_ 128
#define QKS_ 4096
#define BS_ 8192

typedef __attribute__((ext_vector_type(8))) short bfrag8;
typedef __attribute__((ext_vector_type(4))) float ffrag4;

typedef const __attribute__((address_space(1))) void* gptr1;
typedef __attribute__((address_space(3))) void* lptr3;
#define GL16(g, l) __builtin_amdgcn_global_load_lds((gptr1)(g), (lptr3)(l), 16, 0, 0)

__device__ __forceinline__ short f2bf(float f) {
  unsigned u = __float_as_uint(f);
  u = (u + 0x7FFFu + ((u >> 16) & 1u)) >> 16;
  return (short)u;
}
__device__ __forceinline__ float bf2f(short s) {
  return __uint_as_float(((unsigned)(unsigned short)s) << 16);
}
__device__ __forceinline__ unsigned pk2(float lo, float hi) {
  unsigned a = __float_as_uint(lo);
  a = (a + 0x7FFFu + ((a >> 16) & 1u)) >> 16;
  unsigned b = __float_as_uint(hi);
  b = (b + 0x7FFFu + ((b >> 16) & 1u)) & 0xFFFF0000u;
  return a | b;
}

// ---------------- LayerNorm: fp32 X -> bf16 Xn ----------------
__global__ __launch_bounds__(256) void ln_kernel(const float* __restrict__ X,
    const float* __restrict__ w, const float* __restrict__ bta,
    short* __restrict__ Xn) {
  int row = blockIdx.x;
  int tid = threadIdx.x;
  const float* xr = X + (size_t)row * D_;
  float x[8];
  float4 v0 = *(const float4*)(xr + tid * 4);
  float4 v1 = *(const float4*)(xr + 1024 + tid * 4);
  x[0] = v0.x; x[1] = v0.y; x[2] = v0.z; x[3] = v0.w;
  x[4] = v1.x; x[5] = v1.y; x[6] = v1.z; x[7] = v1.w;
  float sum = 0.f, ssq = 0.f;
#pragma unroll
  for (int i = 0; i < 8; i++) { sum += x[i]; ssq += x[i] * x[i]; }
#pragma unroll
  for (int off = 1; off < 64; off <<= 1) {
    sum += __shfl_xor(sum, off, 64);
    ssq += __shfl_xor(ssq, off, 64);
  }
  __shared__ float s1[4], s2[4];
  int wave = tid >> 6;
  if ((tid & 63) == 0) { s1[wave] = sum; s2[wave] = ssq; }
  __syncthreads();
  sum = s1[0] + s1[1] + s1[2] + s1[3];
  ssq = s2[0] + s2[1] + s2[2] + s2[3];
  float mu = sum * (1.0f / D_);
  float var = ssq * (1.0f / D_) - mu * mu;
  float rs = rsqrtf(var + 1e-5f);
  short* orow = Xn + (size_t)row * D_;
#pragma unroll
  for (int i = 0; i < 8; i++) {
    int col = (i < 4) ? (tid * 4 + i) : (1024 + tid * 4 + (i - 4));
    float xn = (x[i] - mu) * rs * w[col] + bta[col];
    orow[col] = f2bf(xn);
  }
}

// ---------------- Transpose + cast: W (RxC fp32) -> WT (CxR bf16) ----------------
__global__ __launch_bounds__(256) void transpose_cvt(const float* __restrict__ W,
    short* __restrict__ WT, int R, int C) {
  __shared__ float t[32][33];
  int tx = threadIdx.x, ty = threadIdx.y;
  int c0 = blockIdx.x * 32, r0 = blockIdx.y * 32;
#pragma unroll
  for (int i = 0; i < 4; i++)
    t[ty + i * 8][tx] = W[(size_t)(r0 + ty + i * 8) * C + c0 + tx];
  __syncthreads();
#pragma unroll
  for (int i = 0; i < 4; i++)
    WT[(size_t)(c0 + ty + i * 8) * R + r0 + tx] = f2bf(t[tx][ty + i * 8]);
}

// ---------------- GEMM: block 256x128, wave-tile 128x64 ----------------
// EPI 0 (QKV): cols<4096 -> Cb (stride 4096) with fused RoPE on (col&127)<64;
//              cols>=4096 -> V written directly in Vt layout (b,h,Dh,S).
// EPI 1: fp32 Cf = acc + resid, stride N.
template<int EPI>
__global__ __launch_bounds__(256, 2) void gemm_bt(const short* __restrict__ A,
    const short* __restrict__ Bt, short* __restrict__ Cb, short* __restrict__ Vt,
    float* __restrict__ Cf, const float* __restrict__ resid, int M, int N, int K) {
  __shared__ __align__(16) short lA[256 * 64];   // 32 KiB
  __shared__ __align__(16) short lB[128 * 64];   // 16 KiB
  int tid = threadIdx.x;
  int m0 = blockIdx.y * 256, n0 = blockIdx.x * 128;
  int wave = tid >> 6, lane = tid & 63;
  int m16 = lane & 15, quad = lane >> 4;
  int wm = (wave >> 1) * 128, wn = (wave & 1) * 64;
  const ffrag4 fzero = {0.f, 0.f, 0.f, 0.f};
  ffrag4 acc[8][4];
#pragma unroll
  for (int i = 0; i < 8; i++)
#pragma unroll
    for (int j = 0; j < 4; j++) acc[i][j] = fzero;

  int srow = lane >> 3;        // 0..7 row within 1 KiB chunk
  int scb  = lane & 7;         // 16B block within row
  for (int k0 = 0; k0 < K; k0 += 64) {
#pragma unroll
    for (int i = 0; i < 8; i++) {
      int c = wave * 8 + i;              // A chunk 0..31
      int r = c * 8 + srow;              // row 0..255
      int sb = scb ^ (r & 7);
      GL16(A + (size_t)(m0 + r) * K + k0 + sb * 8, lA + c * 512);
    }
#pragma unroll
    for (int i = 0; i < 4; i++) {
      int c = wave * 4 + i;              // B chunk 0..15
      int r = c * 8 + srow;              // row 0..127
      int sb = scb ^ (r & 7);
      GL16(Bt + (size_t)(n0 + r) * K + k0 + sb * 8, lB + c * 512);
    }
    __syncthreads();
#pragma unroll
    for (int kk = 0; kk < 2; kk++) {
      bfrag8 af[8], bfb[4];
#pragma unroll
      for (int t = 0; t < 8; t++) {
        int ra = wm + t * 16 + m16;
        af[t] = *(const bfrag8*)(lA + ra * 64 + (((kk * 4 + quad) ^ (ra & 7)) << 3));
      }
#pragma unroll
      for (int t = 0; t < 4; t++) {
        int rb = wn + t * 16 + m16;
        bfb[t] = *(const bfrag8*)(lB + rb * 64 + (((kk * 4 + quad) ^ (rb & 7)) << 3));
      }
#pragma unroll
      for (int i = 0; i < 8; i++)
#pragma unroll
        for (int j = 0; j < 4; j++)
          acc[i][j] = __builtin_amdgcn_mfma_f32_16x16x32_bf16(af[i], bfb[j], acc[i][j], 0, 0, 0);
    }
    __syncthreads();
  }

#pragma unroll
  for (int i = 0; i < 8; i++) {
    int rowb = m0 + wm + i * 16 + quad * 4;
#pragma unroll
    for (int j = 0; j < 4; j++) {
      int col = n0 + wn + j * 16 + m16;
      if (EPI == 1) {
#pragma unroll
        for (int r = 0; r < 4; r++) {
          size_t idx = (size_t)(rowb + r) * N + col;
          Cf[idx] = acc[i][j][r] + resid[idx];
        }
      } else if (col >= 4096) {
        // V: write directly in Vt (b,h,Dh,S) layout, 4 consecutive s as short4
        int d = col - 4096;
        short4 pk;
        pk.x = f2bf(acc[i][j][0]);
        pk.y = f2bf(acc[i][j][1]);
        pk.z = f2bf(acc[i][j][2]);
        pk.w = f2bf(acc[i][j][3]);
        *(short4*)(Vt + ((size_t)((rowb >> 11) * H_ + (d >> 7)) * DH_ + (d & 127)) * S_ +
                   (rowb & (S_ - 1))) = pk;
      } else if ((col & 127) < 64) {
        // fused RoPE on Q/K (first 64 channels of each head)
        int p = (col & 127) >> 1;
        float invf = exp2f(-(float)p * (13.287712379549449f / 32.0f));
        float sgn = (col & 1) ? 1.0f : -1.0f;
#pragma unroll
        for (int r = 0; r < 4; r++) {
          float own = acc[i][j][r];
          float prt = __shfl_xor(own, 1, 64);
          float sn, cs;
          sincosf((float)((rowb + r) & (S_ - 1)) * invf, &sn, &cs);
          Cb[(size_t)(rowb + r) * QKS_ + col] = f2bf(own * cs + sgn * prt * sn);
        }
      } else {
#pragma unroll
        for (int r = 0; r < 4; r++)
          Cb[(size_t)(rowb + r) * QKS_ + col] = f2bf(acc[i][j][r]);
      }
    }
  }
}

// ---------------- Flash attention, S^T form ----------------
__global__ __launch_bounds__(512) void attn_kernel(const short* __restrict__ qkv,
    const short* __restrict__ Vt, short* __restrict__ ctx) {
  __shared__ __align__(16) short lK[2][64 * 128];   // [key][d]  16 KiB each
  __shared__ __align__(16) short lV[2][128 * 64];   // [d][key]  16 KiB each
  int tid = threadIdx.x;
  int wave = tid >> 6, lane = tid & 63;
  int m16 = lane & 15, quad = lane >> 4;
  int bh = blockIdx.y;
  int b = bh >> 4, h = bh & 15;
  int qbase = blockIdx.x * 256 + wave * 32;

  const float qscale = 1.4426950408889634f * 0.08838834764831845f;
  bfrag8 qf[2][4];
#pragma unroll
  for (int qb = 0; qb < 2; qb++)
#pragma unroll
    for (int kc = 0; kc < 4; kc++) {
      bfrag8 q = *(const bfrag8*)(qkv +
          (size_t)(b * S_ + qbase + qb * 16 + m16) * QKS_ + h * DH_ + kc * 32 + quad * 8);
#pragma unroll
      for (int j = 0; j < 8; j++) q[j] = f2bf(bf2f(q[j]) * qscale);
      qf[qb][kc] = q;
    }

  const ffrag4 fzero = {0.f, 0.f, 0.f, 0.f};
  ffrag4 oacc[2][8];
#pragma unroll
  for (int qb = 0; qb < 2; qb++)
#pragma unroll
    for (int nd = 0; nd < 8; nd++) oacc[qb][nd] = fzero;
  float lpart[2] = {0.f, 0.f};

  int krow = lane >> 4;
  int kcb = lane & 15;
  int vrow = lane >> 3;
  int vcb = lane & 7;

  {
#pragma unroll
    for (int i = 0; i < 2; i++) {
      int c = wave + i * 8;
      int r = c * 4 + krow;
      int sb = kcb ^ (r & 15);
      GL16(qkv + (size_t)(b * S_ + r) * QKS_ + D_ + h * DH_ + sb * 8, &lK[0][c * 512]);
    }
#pragma unroll
    for (int i = 0; i < 2; i++) {
      int c = wave + i * 8;
      int r = c * 8 + vrow;
      int sb = vcb ^ (r & 7);
      GL16(Vt + (size_t)(bh * DH_ + r) * S_ + sb * 8, &lV[0][c * 512]);
    }
  }
  __syncthreads();

  for (int kt = 0; kt < 32; kt++) {
    int cur = kt & 1;
    if (kt < 31) {
      int sk0 = (kt + 1) * 64;
      int nb = cur ^ 1;
#pragma unroll
      for (int i = 0; i < 2; i++) {
        int c = wave + i * 8;
        int r = c * 4 + krow;
        int sb = kcb ^ (r & 15);
        GL16(qkv + (size_t)(b * S_ + sk0 + r) * QKS_ + D_ + h * DH_ + sb * 8, &lK[nb][c * 512]);
      }
#pragma unroll
      for (int i = 0; i < 2; i++) {
        int c = wave + i * 8;
        int r = c * 8 + vrow;
        int sb = vcb ^ (r & 7);
        GL16(Vt + (size_t)(bh * DH_ + r) * S_ + sk0 + sb * 8, &lV[nb][c * 512]);
      }
    }

    const short* kb = &lK[cur][0];
    const short* vb = &lV[cur][0];

    ffrag4 sacc[2][4];
#pragma unroll
    for (int qb = 0; qb < 2; qb++)
#pragma unroll
      for (int ntk = 0; ntk < 4; ntk++) sacc[qb][ntk] = fzero;
#pragma unroll
    for (int ntk = 0; ntk < 4; ntk++)
#pragma unroll
      for (int kc = 0; kc < 4; kc++) {
        bfrag8 kf = *(const bfrag8*)(kb + (ntk * 16 + m16) * 128 +
                                     (((kc * 4 + quad) ^ m16) << 3));
        sacc[0][ntk] = __builtin_amdgcn_mfma_f32_16x16x32_bf16(kf, qf[0][kc], sacc[0][ntk], 0, 0, 0);
        sacc[1][ntk] = __builtin_amdgcn_mfma_f32_16x16x32_bf16(kf, qf[1][kc], sacc[1][ntk], 0, 0, 0);
      }

    bfrag8 pA[2][2];
#pragma unroll
    for (int qb = 0; qb < 2; qb++) {
      unsigned Xp[4][2];
      float ls = 0.f;
#pragma unroll
      for (int ntk = 0; ntk < 4; ntk++) {
        float e0 = exp2f(sacc[qb][ntk][0]);
        float e1 = exp2f(sacc[qb][ntk][1]);
        float e2 = exp2f(sacc[qb][ntk][2]);
        float e3 = exp2f(sacc[qb][ntk][3]);
        ls += (e0 + e1) + (e2 + e3);
        Xp[ntk][0] = pk2(e0, e1);
        Xp[ntk][1] = pk2(e2, e3);
      }
      lpart[qb] += ls;
#pragma unroll
      for (int kc = 0; kc < 2; kc++) {
        unsigned x0 = Xp[2 * kc][0], x1 = Xp[2 * kc][1];
        unsigned y0 = Xp[2 * kc + 1][0], y1 = Xp[2 * kc + 1][1];
        asm("v_permlane32_swap_b32 %0, %1" : "+v"(x0), "+v"(y0));
        asm("v_permlane16_swap_b32 %0, %1" : "+v"(x0), "+v"(y0));
        asm("v_permlane32_swap_b32 %0, %1" : "+v"(x1), "+v"(y1));
        asm("v_permlane16_swap_b32 %0, %1" : "+v"(x1), "+v"(y1));
        union { int4 i4; bfrag8 b8; } u;
        u.i4 = (int4){(int)x0, (int)x1, (int)y0, (int)y1};
        pA[qb][kc] = u.b8;
      }
    }

#pragma unroll
    for (int kc = 0; kc < 2; kc++)
#pragma unroll
      for (int nd = 0; nd < 8; nd++) {
        bfrag8 vf = *(const bfrag8*)(vb + (nd * 16 + m16) * 64 +
                                     (((kc * 4 + quad) ^ (m16 & 7)) << 3));
        oacc[0][nd] = __builtin_amdgcn_mfma_f32_16x16x32_bf16(pA[0][kc], vf, oacc[0][nd], 0, 0, 0);
        oacc[1][nd] = __builtin_amdgcn_mfma_f32_16x16x32_bf16(pA[1][kc], vf, oacc[1][nd], 0, 0, 0);
      }

    __syncthreads();
  }

#pragma unroll
  for (int qb = 0; qb < 2; qb++) {
    lpart[qb] += __shfl_xor(lpart[qb], 16, 64);
    lpart[qb] += __shfl_xor(lpart[qb], 32, 64);
  }
#pragma unroll
  for (int qb = 0; qb < 2; qb++) {
    float inv[4];
#pragma unroll
    for (int r = 0; r < 4; r++) inv[r] = 1.0f / __shfl(lpart[qb], quad * 4 + r, 64);
#pragma unroll
    for (int nd = 0; nd < 8; nd++)
#pragma unroll
      for (int r = 0; r < 4; r++) {
        int row = qbase + qb * 16 + quad * 4 + r;
        int col = h * DH_ + nd * 16 + m16;
        ctx[(size_t)(b * S_ + row) * D_ + col] = f2bf(oacc[qb][nd][r] * inv[r]);
      }
  }
}

// ---------------- launch ----------------
extern "C" void kernel_launch(void* const* d_in, const int* in_sizes, int n_in,
                              void* d_out, int out_size, void* d_ws, size_t ws_size,
                              hipStream_t stream) {
  const float* X    = (const float*)d_in[0];
  const float* lnw  = (const float*)d_in[1];
  const float* lnb  = (const float*)d_in[2];
  const float* Win  = (const float*)d_in[3];
  const float* Wout = (const float*)d_in[4];
  float* out = (float*)d_out;
  char* ws = (char*)d_ws;
  short* Xn    = (short*)(ws + 0);          //  32 MiB: 8192x2048 bf16
  short* WinT  = (short*)(ws + 33554432);   //  24 MiB: 6144x2048 bf16
  short* WoutT = (short*)(ws + 58720256);   //   8 MiB: 2048x2048 bf16
  short* qkv   = (short*)(ws + 67108864);   //  64 MiB: 8192x4096 bf16 (Q,K only)
  short* Vt    = (short*)(ws + 134217728);  //  32 MiB: (b,h,128,2048) bf16
  short* ctx   = (short*)(ws + 167772160);  //  32 MiB: 8192x2048 bf16

  transpose_cvt<<<dim3(192, 64), dim3(32, 8), 0, stream>>>(Win, WinT, 2048, 6144);
  transpose_cvt<<<dim3(64, 64), dim3(32, 8), 0, stream>>>(Wout, WoutT, 2048, 2048);
  ln_kernel<<<8192, 256, 0, stream>>>(X, lnw, lnb, Xn);
  gemm_bt<0><<<dim3(48, 32), 256, 0, stream>>>(Xn, WinT, qkv, Vt, nullptr, nullptr, 8192, 6144, 2048);
  attn_kernel<<<dim3(8, 64), 512, 0, stream>>>(qkv, Vt, ctx);
  gemm_bt<1><<<dim3(16, 32), 256, 0, stream>>>(ctx, WoutT, nullptr, nullptr, out, X, 8192, 2048, 2048);
}

// Round 4
// 713.958 us; speedup vs baseline: 2.2292x; 2.2292x over previous
//
#include <hip/hip_runtime.h>
#include <hip/hip_bf16.h>
#include <cstddef>

#define B_ 4
#define S_ 2048
#define D_ 2048
#define H_ 16
#define DH_ 128
#define QKS_ 4096
#define BS_ 8192

typedef __attribute__((ext_vector_type(8))) short bfrag8;
typedef __attribute__((ext_vector_type(4))) float ffrag4;

typedef const __attribute__((address_space(1))) void* gptr1;
typedef __attribute__((address_space(3))) void* lptr3;
#define GL16(g, l) __builtin_amdgcn_global_load_lds((gptr1)(g), (lptr3)(l), 16, 0, 0)

__device__ __forceinline__ short f2bf(float f) {
  unsigned u = __float_as_uint(f);
  u = (u + 0x7FFFu + ((u >> 16) & 1u)) >> 16;
  return (short)u;
}
__device__ __forceinline__ float bf2f(short s) {
  return __uint_as_float(((unsigned)(unsigned short)s) << 16);
}
__device__ __forceinline__ unsigned pk2(float lo, float hi) {
  unsigned a = __float_as_uint(lo);
  a = (a + 0x7FFFu + ((a >> 16) & 1u)) >> 16;
  unsigned b = __float_as_uint(hi);
  b = (b + 0x7FFFu + ((b >> 16) & 1u)) & 0xFFFF0000u;
  return a | b;
}

// ---------------- RoPE cos/sin table: tab[s*32+p] = {cos,sin}(s * 10000^(-2p/64)) ----------------
__global__ __launch_bounds__(256) void rope_tab_kernel(float2* __restrict__ tab) {
  int idx = blockIdx.x * 256 + threadIdx.x;   // 65536
  int s = idx >> 5, p = idx & 31;
  float invf = exp2f(-(float)p * (13.287712379549449f / 32.0f));
  float sn, cs;
  sincosf((float)s * invf, &sn, &cs);
  tab[idx] = make_float2(cs, sn);
}

// ---------------- LayerNorm: fp32 X -> bf16 Xn ----------------
__global__ __launch_bounds__(256) void ln_kernel(const float* __restrict__ X,
    const float* __restrict__ w, const float* __restrict__ bta,
    short* __restrict__ Xn) {
  int row = blockIdx.x;
  int tid = threadIdx.x;
  const float* xr = X + (size_t)row * D_;
  float x[8];
  float4 v0 = *(const float4*)(xr + tid * 4);
  float4 v1 = *(const float4*)(xr + 1024 + tid * 4);
  x[0] = v0.x; x[1] = v0.y; x[2] = v0.z; x[3] = v0.w;
  x[4] = v1.x; x[5] = v1.y; x[6] = v1.z; x[7] = v1.w;
  float sum = 0.f, ssq = 0.f;
#pragma unroll
  for (int i = 0; i < 8; i++) { sum += x[i]; ssq += x[i] * x[i]; }
#pragma unroll
  for (int off = 1; off < 64; off <<= 1) {
    sum += __shfl_xor(sum, off, 64);
    ssq += __shfl_xor(ssq, off, 64);
  }
  __shared__ float s1[4], s2[4];
  int wave = tid >> 6;
  if ((tid & 63) == 0) { s1[wave] = sum; s2[wave] = ssq; }
  __syncthreads();
  sum = s1[0] + s1[1] + s1[2] + s1[3];
  ssq = s2[0] + s2[1] + s2[2] + s2[3];
  float mu = sum * (1.0f / D_);
  float var = ssq * (1.0f / D_) - mu * mu;
  float rs = rsqrtf(var + 1e-5f);
  short* orow = Xn + (size_t)row * D_;
#pragma unroll
  for (int i = 0; i < 8; i++) {
    int col = (i < 4) ? (tid * 4 + i) : (1024 + tid * 4 + (i - 4));
    float xn = (x[i] - mu) * rs * w[col] + bta[col];
    orow[col] = f2bf(xn);
  }
}

// ---------------- Transpose + cast: W (RxC fp32) -> WT (CxR bf16) ----------------
__global__ __launch_bounds__(256) void transpose_cvt(const float* __restrict__ W,
    short* __restrict__ WT, int R, int C) {
  __shared__ float t[32][33];
  int tx = threadIdx.x, ty = threadIdx.y;
  int c0 = blockIdx.x * 32, r0 = blockIdx.y * 32;
#pragma unroll
  for (int i = 0; i < 4; i++)
    t[ty + i * 8][tx] = W[(size_t)(r0 + ty + i * 8) * C + c0 + tx];
  __syncthreads();
#pragma unroll
  for (int i = 0; i < 4; i++)
    WT[(size_t)(c0 + ty + i * 8) * R + r0 + tx] = f2bf(t[tx][ty + i * 8]);
}

// ---------------- GEMM: block 128x128, wave-tile 64x64 (round-2 proven structure) ----------------
// EPI 0 (QKV, N=6144): cols<4096 -> Cb (stride 4096) w/ table-RoPE on (col&127)<64;
//                      cols>=4096 -> V direct in Vt layout (b,h,Dh,S) as short4.
// EPI 1: fp32 Cf = acc + resid, stride N.
template<int EPI>
__global__ __launch_bounds__(256) void gemm_bt(const short* __restrict__ A,
    const short* __restrict__ Bt, short* __restrict__ Cb, short* __restrict__ Vt,
    const float2* __restrict__ tab, float* __restrict__ Cf,
    const float* __restrict__ resid, int M, int N, int K) {
  __shared__ __align__(16) short lA[128 * 64];
  __shared__ __align__(16) short lB[128 * 64];
  int tid = threadIdx.x;
  int m0 = blockIdx.y * 128, n0 = blockIdx.x * 128;
  int wave = tid >> 6, lane = tid & 63;
  int m16 = lane & 15, quad = lane >> 4;
  int wm = (wave >> 1) * 64, wn = (wave & 1) * 64;
  const ffrag4 fzero = {0.f, 0.f, 0.f, 0.f};
  ffrag4 acc[4][4];
#pragma unroll
  for (int i = 0; i < 4; i++)
#pragma unroll
    for (int j = 0; j < 4; j++) acc[i][j] = fzero;

  int srow = lane >> 3;
  int scb  = lane & 7;
  for (int k0 = 0; k0 < K; k0 += 64) {
#pragma unroll
    for (int i = 0; i < 4; i++) {
      int c = i * 4 + wave;
      int r = c * 8 + srow;
      int sb = scb ^ (r & 7);
      GL16(A + (size_t)(m0 + r) * K + k0 + sb * 8, lA + c * 512);
      GL16(Bt + (size_t)(n0 + r) * K + k0 + sb * 8, lB + c * 512);
    }
    __syncthreads();
#pragma unroll
    for (int kk = 0; kk < 2; kk++) {
      bfrag8 af[4], bfb[4];
#pragma unroll
      for (int t = 0; t < 4; t++) {
        int ra = wm + t * 16 + m16;
        int rb = wn + t * 16 + m16;
        int blk = kk * 4 + quad;
        af[t] = *(const bfrag8*)(lA + ra * 64 + ((blk ^ (ra & 7)) << 3));
        bfb[t] = *(const bfrag8*)(lB + rb * 64 + ((blk ^ (rb & 7)) << 3));
      }
#pragma unroll
      for (int i = 0; i < 4; i++)
#pragma unroll
        for (int j = 0; j < 4; j++)
          acc[i][j] = __builtin_amdgcn_mfma_f32_16x16x32_bf16(af[i], bfb[j], acc[i][j], 0, 0, 0);
    }
    __syncthreads();
  }

#pragma unroll
  for (int i = 0; i < 4; i++) {
    int rowb = m0 + wm + i * 16 + quad * 4;
#pragma unroll
    for (int j = 0; j < 4; j++) {
      int col = n0 + wn + j * 16 + m16;
      if (EPI == 1) {
#pragma unroll
        for (int r = 0; r < 4; r++) {
          size_t idx = (size_t)(rowb + r) * N + col;
          Cf[idx] = acc[i][j][r] + resid[idx];
        }
      } else if (n0 >= 4096) {
        // V: direct store in Vt (b,h,Dh,S) layout, 4 consecutive s as short4
        int d = col - 4096;
        short4 pk;
        pk.x = f2bf(acc[i][j][0]);
        pk.y = f2bf(acc[i][j][1]);
        pk.z = f2bf(acc[i][j][2]);
        pk.w = f2bf(acc[i][j][3]);
        *(short4*)(Vt + ((size_t)((rowb >> 11) * H_ + (d >> 7)) * DH_ + (d & 127)) * S_ +
                   (rowb & (S_ - 1))) = pk;
      } else if ((col & 127) < 64) {
        // fused RoPE on Q/K via table
        int p = (col & 127) >> 1;
        float sgn = (col & 1) ? 1.0f : -1.0f;
#pragma unroll
        for (int r = 0; r < 4; r++) {
          float own = acc[i][j][r];
          float prt = __shfl_xor(own, 1, 64);
          float2 cssn = tab[((rowb + r) & (S_ - 1)) * 32 + p];
          Cb[(size_t)(rowb + r) * QKS_ + col] = f2bf(own * cssn.x + sgn * prt * cssn.y);
        }
      } else {
#pragma unroll
        for (int r = 0; r < 4; r++)
          Cb[(size_t)(rowb + r) * QKS_ + col] = f2bf(acc[i][j][r]);
      }
    }
  }
}

// ---------------- Flash attention, S^T form ----------------
__global__ __launch_bounds__(512) void attn_kernel(const short* __restrict__ qkv,
    const short* __restrict__ Vt, short* __restrict__ ctx) {
  __shared__ __align__(16) short lK[2][64 * 128];   // [key][d]  16 KiB each
  __shared__ __align__(16) short lV[2][128 * 64];   // [d][key]  16 KiB each
  int tid = threadIdx.x;
  int wave = tid >> 6, lane = tid & 63;
  int m16 = lane & 15, quad = lane >> 4;
  int bh = blockIdx.y;
  int b = bh >> 4, h = bh & 15;
  int qbase = blockIdx.x * 256 + wave * 32;

  const float qscale = 1.4426950408889634f * 0.08838834764831845f;
  bfrag8 qf[2][4];
#pragma unroll
  for (int qb = 0; qb < 2; qb++)
#pragma unroll
    for (int kc = 0; kc < 4; kc++) {
      bfrag8 q = *(const bfrag8*)(qkv +
          (size_t)(b * S_ + qbase + qb * 16 + m16) * QKS_ + h * DH_ + kc * 32 + quad * 8);
#pragma unroll
      for (int j = 0; j < 8; j++) q[j] = f2bf(bf2f(q[j]) * qscale);
      qf[qb][kc] = q;
    }

  const ffrag4 fzero = {0.f, 0.f, 0.f, 0.f};
  ffrag4 oacc[2][8];
#pragma unroll
  for (int qb = 0; qb < 2; qb++)
#pragma unroll
    for (int nd = 0; nd < 8; nd++) oacc[qb][nd] = fzero;
  float lpart[2] = {0.f, 0.f};

  int krow = lane >> 4;
  int kcb = lane & 15;
  int vrow = lane >> 3;
  int vcb = lane & 7;

  {
#pragma unroll
    for (int i = 0; i < 2; i++) {
      int c = wave + i * 8;
      int r = c * 4 + krow;
      int sb = kcb ^ (r & 15);
      GL16(qkv + (size_t)(b * S_ + r) * QKS_ + D_ + h * DH_ + sb * 8, &lK[0][c * 512]);
    }
#pragma unroll
    for (int i = 0; i < 2; i++) {
      int c = wave + i * 8;
      int r = c * 8 + vrow;
      int sb = vcb ^ (r & 7);
      GL16(Vt + (size_t)(bh * DH_ + r) * S_ + sb * 8, &lV[0][c * 512]);
    }
  }
  __syncthreads();

  for (int kt = 0; kt < 32; kt++) {
    int cur = kt & 1;
    if (kt < 31) {
      int sk0 = (kt + 1) * 64;
      int nb = cur ^ 1;
#pragma unroll
      for (int i = 0; i < 2; i++) {
        int c = wave + i * 8;
        int r = c * 4 + krow;
        int sb = kcb ^ (r & 15);
        GL16(qkv + (size_t)(b * S_ + sk0 + r) * QKS_ + D_ + h * DH_ + sb * 8, &lK[nb][c * 512]);
      }
#pragma unroll
      for (int i = 0; i < 2; i++) {
        int c = wave + i * 8;
        int r = c * 8 + vrow;
        int sb = vcb ^ (r & 7);
        GL16(Vt + (size_t)(bh * DH_ + r) * S_ + sk0 + sb * 8, &lV[nb][c * 512]);
      }
    }

    const short* kb = &lK[cur][0];
    const short* vb = &lV[cur][0];

    ffrag4 sacc[2][4];
#pragma unroll
    for (int qb = 0; qb < 2; qb++)
#pragma unroll
      for (int ntk = 0; ntk < 4; ntk++) sacc[qb][ntk] = fzero;
#pragma unroll
    for (int ntk = 0; ntk < 4; ntk++)
#pragma unroll
      for (int kc = 0; kc < 4; kc++) {
        bfrag8 kf = *(const bfrag8*)(kb + (ntk * 16 + m16) * 128 +
                                     (((kc * 4 + quad) ^ m16) << 3));
        sacc[0][ntk] = __builtin_amdgcn_mfma_f32_16x16x32_bf16(kf, qf[0][kc], sacc[0][ntk], 0, 0, 0);
        sacc[1][ntk] = __builtin_amdgcn_mfma_f32_16x16x32_bf16(kf, qf[1][kc], sacc[1][ntk], 0, 0, 0);
      }

    bfrag8 pA[2][2];
#pragma unroll
    for (int qb = 0; qb < 2; qb++) {
      unsigned Xp[4][2];
      float ls = 0.f;
#pragma unroll
      for (int ntk = 0; ntk < 4; ntk++) {
        float e0 = exp2f(sacc[qb][ntk][0]);
        float e1 = exp2f(sacc[qb][ntk][1]);
        float e2 = exp2f(sacc[qb][ntk][2]);
        float e3 = exp2f(sacc[qb][ntk][3]);
        ls += (e0 + e1) + (e2 + e3);
        Xp[ntk][0] = pk2(e0, e1);
        Xp[ntk][1] = pk2(e2, e3);
      }
      lpart[qb] += ls;
#pragma unroll
      for (int kc = 0; kc < 2; kc++) {
        unsigned x0 = Xp[2 * kc][0], x1 = Xp[2 * kc][1];
        unsigned y0 = Xp[2 * kc + 1][0], y1 = Xp[2 * kc + 1][1];
        asm("v_permlane32_swap_b32 %0, %1" : "+v"(x0), "+v"(y0));
        asm("v_permlane16_swap_b32 %0, %1" : "+v"(x0), "+v"(y0));
        asm("v_permlane32_swap_b32 %0, %1" : "+v"(x1), "+v"(y1));
        asm("v_permlane16_swap_b32 %0, %1" : "+v"(x1), "+v"(y1));
        union { int4 i4; bfrag8 b8; } u;
        u.i4 = (int4){(int)x0, (int)x1, (int)y0, (int)y1};
        pA[qb][kc] = u.b8;
      }
    }

#pragma unroll
    for (int kc = 0; kc < 2; kc++)
#pragma unroll
      for (int nd = 0; nd < 8; nd++) {
        bfrag8 vf = *(const bfrag8*)(vb + (nd * 16 + m16) * 64 +
                                     (((kc * 4 + quad) ^ (m16 & 7)) << 3));
        oacc[0][nd] = __builtin_amdgcn_mfma_f32_16x16x32_bf16(pA[0][kc], vf, oacc[0][nd], 0, 0, 0);
        oacc[1][nd] = __builtin_amdgcn_mfma_f32_16x16x32_bf16(pA[1][kc], vf, oacc[1][nd], 0, 0, 0);
      }

    __syncthreads();
  }

#pragma unroll
  for (int qb = 0; qb < 2; qb++) {
    lpart[qb] += __shfl_xor(lpart[qb], 16, 64);
    lpart[qb] += __shfl_xor(lpart[qb], 32, 64);
  }
#pragma unroll
  for (int qb = 0; qb < 2; qb++) {
    float inv[4];
#pragma unroll
    for (int r = 0; r < 4; r++) inv[r] = 1.0f / __shfl(lpart[qb], quad * 4 + r, 64);
#pragma unroll
    for (int nd = 0; nd < 8; nd++)
#pragma unroll
      for (int r = 0; r < 4; r++) {
        int row = qbase + qb * 16 + quad * 4 + r;
        int col = h * DH_ + nd * 16 + m16;
        ctx[(size_t)(b * S_ + row) * D_ + col] = f2bf(oacc[qb][nd][r] * inv[r]);
      }
  }
}

// ---------------- launch ----------------
extern "C" void kernel_launch(void* const* d_in, const int* in_sizes, int n_in,
                              void* d_out, int out_size, void* d_ws, size_t ws_size,
                              hipStream_t stream) {
  const float* X    = (const float*)d_in[0];
  const float* lnw  = (const float*)d_in[1];
  const float* lnb  = (const float*)d_in[2];
  const float* Win  = (const float*)d_in[3];
  const float* Wout = (const float*)d_in[4];
  float* out = (float*)d_out;
  char* ws = (char*)d_ws;
  short*  Xn    = (short*)(ws + 0);          //  32 MiB: 8192x2048 bf16
  short*  WinT  = (short*)(ws + 33554432);   //  24 MiB: 6144x2048 bf16
  short*  WoutT = (short*)(ws + 58720256);   //   8 MiB: 2048x2048 bf16
  short*  qkv   = (short*)(ws + 67108864);   //  64 MiB: 8192x4096 bf16 (Q,K only)
  short*  Vt    = (short*)(ws + 134217728);  //  32 MiB: (b,h,128,2048) bf16
  short*  ctx   = (short*)(ws + 167772160);  //  32 MiB: 8192x2048 bf16
  float2* tab   = (float2*)(ws + 201326592); // 512 KiB: 2048x32 cos/sin

  rope_tab_kernel<<<256, 256, 0, stream>>>(tab);
  transpose_cvt<<<dim3(192, 64), dim3(32, 8), 0, stream>>>(Win, WinT, 2048, 6144);
  transpose_cvt<<<dim3(64, 64), dim3(32, 8), 0, stream>>>(Wout, WoutT, 2048, 2048);
  ln_kernel<<<8192, 256, 0, stream>>>(X, lnw, lnb, Xn);
  gemm_bt<0><<<dim3(48, 64), 256, 0, stream>>>(Xn, WinT, qkv, Vt, tab, nullptr, nullptr, 8192, 6144, 2048);
  attn_kernel<<<dim3(8, 64), 512, 0, stream>>>(qkv, Vt, ctx);
  gemm_bt<1><<<dim3(16, 64), 256, 0, stream>>>(ctx, WoutT, nullptr, nullptr, nullptr, out, X, 8192, 2048, 2048);
}